// Round 11
// baseline (54.214 us; speedup 1.0000x reference)
//
#include <hip/hip_runtime.h>
#include <math.h>

#define TT   16384
#define ADIM 1024
#define NCH  1024    // k3 blocks (16 rows each)
#define RPB  16      // rows per block

// fast tanh: 1 - 2/(e^{2x}+1); saturates correctly for large |x|
__device__ __forceinline__ float ftanh(float x) {
    float e2 = __expf(2.0f * x);
    return 1.0f - 2.0f * __builtin_amdgcn_rcpf(e2 + 1.0f);
}

__device__ __forceinline__ float pdot(float4 p, float4 d, float4 g) {
    return ftanh(p.x + d.x) * g.x + ftanh(p.y + d.y) * g.y +
           ftanh(p.z + d.z) * g.z + ftanh(p.w + d.w) * g.w;
}

// K1: dec GEMV partials. grid=256, block b handles rows [4b, 4b+4)
__global__ void k1_gemv_part(const float* __restrict__ z, const float* __restrict__ W,
                             float* __restrict__ part) {
    int b = blockIdx.x, tid = threadIdx.x;
    float4 acc = {0.f, 0.f, 0.f, 0.f};
#pragma unroll
    for (int i = 0; i < 4; ++i) {
        int d = b * 4 + i;
        float zv = z[d];
        float4 w4 = reinterpret_cast<const float4*>(W)[(size_t)d * 256 + tid];
        acc.x += zv * w4.x; acc.y += zv * w4.y; acc.z += zv * w4.z; acc.w += zv * w4.w;
    }
    reinterpret_cast<float4*>(part)[(size_t)b * 256 + tid] = acc;
}

// K2: reduce 256 partials -> dp[1024]. grid=64, block b covers cols [16b,16b+16)
__global__ void k2_gemv_red(const float* __restrict__ part, const float* __restrict__ bdec,
                            float* __restrict__ dp) {
    int b = blockIdx.x, tid = threadIdx.x;
    int lane = tid & 63, wv = tid >> 6;
    int rsub = lane >> 2;
    int colg = lane & 3;
    float4 acc = {0.f, 0.f, 0.f, 0.f};
#pragma unroll
    for (int i = 0; i < 4; ++i) {
        int row = i * 64 + wv * 16 + rsub;
        float4 v = reinterpret_cast<const float4*>(part)[(size_t)row * 256 + b * 4 + colg];
        acc.x += v.x; acc.y += v.y; acc.z += v.z; acc.w += v.w;
    }
#pragma unroll
    for (int off = 4; off <= 32; off <<= 1) {
        acc.x += __shfl_xor(acc.x, off, 64);
        acc.y += __shfl_xor(acc.y, off, 64);
        acc.z += __shfl_xor(acc.z, off, 64);
        acc.w += __shfl_xor(acc.w, off, 64);
    }
    __shared__ float4 lds[4][4];
    if (lane < 4) lds[wv][lane] = acc;
    __syncthreads();
    if (tid < 4) {
        float4 t = {0.f, 0.f, 0.f, 0.f};
#pragma unroll
        for (int w = 0; w < 4; ++w) {
            float4 v = lds[w][tid];
            t.x += v.x; t.y += v.y; t.z += v.z; t.w += v.w;
        }
        float4 bd = reinterpret_cast<const float4*>(bdec)[b * 4 + tid];
        t.x += bd.x; t.y += bd.y; t.z += bd.z; t.w += bd.w;
        reinterpret_cast<float4*>(dp)[b * 4 + tid] = t;
    }
}

// K3: fused e-score + softmax context partials; column-sliced waves.
// grid=NCH x 256. Block b rows [16b, 16b+16). Wave wv owns feature cols
// [256*wv, 256*wv+256) for ALL 16 rows; lane owns one float4 of that slice.
__global__ void __launch_bounds__(256) k3_fused(
    const float* __restrict__ pre, const float* __restrict__ enc,
    const float* __restrict__ dp, const float* __restrict__ wg,
    const float* __restrict__ bgp, const float* __restrict__ mask,
    float* __restrict__ e_out, float* __restrict__ m_out,
    float* __restrict__ s_out, float* __restrict__ cpart) {
    int b = blockIdx.x, tid = threadIdx.x;
    int lane = tid & 63, wv = tid >> 6;
    int col = wv * 64 + lane;   // float4 column index within 256
    float4 d4 = reinterpret_cast<const float4*>(dp)[col];
    float4 g4 = reinterpret_cast<const float4*>(wg)[col];
    float bgv = bgp[0];
    int t0 = b * RPB;
    const float4* pb = reinterpret_cast<const float4*>(pre) + (size_t)t0 * 256 + col;
    const float4* eb = reinterpret_cast<const float4*>(enc) + (size_t)t0 * 256 + col;

    // Phase A: partial dots over this wave's 256-feature slice, 16 rows
    float dt[RPB];
#pragma unroll
    for (int r = 0; r < RPB; ++r) dt[r] = pdot(pb[r * 256], d4, g4);
#pragma unroll
    for (int r = 0; r < RPB; ++r) {
#pragma unroll
        for (int off = 32; off; off >>= 1) dt[r] += __shfl_xor(dt[r], off, 64);
    }
    __shared__ float sd[4][RPB];
    if (lane == 0) {
#pragma unroll
        for (int r = 0; r < RPB; ++r) sd[wv][r] = dt[r];
    }
    __syncthreads();
    float et[RPB];
#pragma unroll
    for (int r = 0; r < RPB; ++r)
        et[r] = 2.0f * (sd[0][r] + sd[1][r] + sd[2][r] + sd[3][r] + bgv + mask[t0 + r]);
    if (tid == 0) {
#pragma unroll
        for (int r = 0; r < RPB; ++r) e_out[t0 + r] = et[r];
    }

    // Phase B: block-local softmax pieces (computed redundantly in all threads)
    float m = et[0];
#pragma unroll
    for (int r = 1; r < RPB; ++r) m = fmaxf(m, et[r]);
    float p[RPB], s = 0.f;
#pragma unroll
    for (int r = 0; r < RPB; ++r) { p[r] = __expf(et[r] - m); s += p[r]; }
    if (tid == 0) { m_out[b] = m; s_out[b] = s; }

    // Phase C: weighted accumulation over enc slice, 16 rows
    float4 ca = {0.f, 0.f, 0.f, 0.f};
#pragma unroll
    for (int r = 0; r < RPB; ++r) {
        float4 ev = eb[r * 256];
        ca.x += p[r] * ev.x; ca.y += p[r] * ev.y;
        ca.z += p[r] * ev.z; ca.w += p[r] * ev.w;
    }
    // each wave writes its own disjoint column slice — no cross-wave combine
    reinterpret_cast<float4*>(cpart)[(size_t)b * 256 + col] = ca;
}

// K4: final. grid=32 x 256. Every block redundantly reduces global M, S
// (NCH m/s entries, 8KB) and builds scale table in LDS. Blocks 0..15 then
// produce 64 c-columns each from cpart; blocks 16..31 produce w from e.
__global__ void __launch_bounds__(256) k4_final(
    const float* __restrict__ m_arr, const float* __restrict__ s_arr,
    const float* __restrict__ cpart, const float* __restrict__ e,
    float* __restrict__ c_out, float* __restrict__ w_out) {
    int b = blockIdx.x, tid = threadIdx.x;
    int lane = tid & 63, wv = tid >> 6;
    __shared__ float redm[4], reds[4];
    __shared__ float sc[NCH];
    // global max M over NCH chunk maxima (NCH/256 = 4 per thread via float4)
    float4 mv = reinterpret_cast<const float4*>(m_arr)[tid];
    float mloc = fmaxf(fmaxf(mv.x, mv.y), fmaxf(mv.z, mv.w));
#pragma unroll
    for (int off = 32; off; off >>= 1) mloc = fmaxf(mloc, __shfl_xor(mloc, off, 64));
    if (lane == 0) redm[wv] = mloc;
    __syncthreads();
    float M = fmaxf(fmaxf(redm[0], redm[1]), fmaxf(redm[2], redm[3]));
    // scale table + S
    float4 sv = reinterpret_cast<const float4*>(s_arr)[tid];
    float4 scl;
    scl.x = __expf(mv.x - M); scl.y = __expf(mv.y - M);
    scl.z = __expf(mv.z - M); scl.w = __expf(mv.w - M);
    reinterpret_cast<float4*>(sc)[tid] = scl;
    float sl = sv.x * scl.x + sv.y * scl.y + sv.z * scl.z + sv.w * scl.w;
#pragma unroll
    for (int off = 32; off; off >>= 1) sl += __shfl_xor(sl, off, 64);
    if (lane == 0) reds[wv] = sl;
    __syncthreads();
    float invS = 1.0f / (reds[0] + reds[1] + reds[2] + reds[3]);

    if (b < 16) {
        // c columns [64b, 64b+64): 16 float4-cols x 16 row-groups
        int rs = tid >> 4;   // row-group 0..15
        int cg = tid & 15;   // float4-col 0..15 within block's 16
        float4 acc = {0.f, 0.f, 0.f, 0.f};
        for (int r = rs; r < NCH; r += 16) {
            float scf = sc[r];
            float4 v = reinterpret_cast<const float4*>(cpart)[(size_t)r * 256 + b * 16 + cg];
            acc.x += scf * v.x; acc.y += scf * v.y;
            acc.z += scf * v.z; acc.w += scf * v.w;
        }
        __shared__ float4 lds[16][16];
        lds[rs][cg] = acc;
        __syncthreads();
        if (tid < 16) {
            float4 t = {0.f, 0.f, 0.f, 0.f};
#pragma unroll
            for (int r = 0; r < 16; ++r) {
                float4 v = lds[r][tid];
                t.x += v.x; t.y += v.y; t.z += v.z; t.w += v.w;
            }
            t.x *= invS; t.y *= invS; t.z *= invS; t.w *= invS;
            reinterpret_cast<float4*>(c_out)[b * 16 + tid] = t;
        }
    } else {
        int base = (b - 16) * 256 + tid;
        float4 ev = reinterpret_cast<const float4*>(e)[base];
        float4 w;
        w.x = __expf(ev.x - M) * invS;
        w.y = __expf(ev.y - M) * invS;
        w.z = __expf(ev.z - M) * invS;
        w.w = __expf(ev.w - M) * invS;
        reinterpret_cast<float4*>(w_out)[base] = w;
    }
}

extern "C" void kernel_launch(void* const* d_in, const int* in_sizes, int n_in,
                              void* d_out, int out_size, void* d_ws, size_t ws_size,
                              hipStream_t stream) {
    const float* dec_z = (const float*)d_in[0];
    // d_in[1] = att_prev (unused)
    const float* pre   = (const float*)d_in[2];
    const float* enc   = (const float*)d_in[3];
    const float* mask  = (const float*)d_in[4];
    const float* W_dec = (const float*)d_in[5];
    const float* b_dec = (const float*)d_in[6];
    const float* wg    = (const float*)d_in[7];
    const float* bg    = (const float*)d_in[8];

    float* out   = (float*)d_out;
    float* c_out = out;            // [1024]
    float* w_out = out + ADIM;     // [16384]

    float* ws = (float*)d_ws;
    float* part   = ws;                           // 256*1024
    float* dp     = part + 256 * ADIM;            // 1024
    float* e_sc   = dp + ADIM;                    // 16384
    float* m_arr  = e_sc + TT;                    // NCH
    float* s_arr  = m_arr + NCH;                  // NCH
    float* cpart  = s_arr + NCH;                  // NCH*1024 (4MB)

    k1_gemv_part<<<256, 256, 0, stream>>>(dec_z, W_dec, part);
    k2_gemv_red<<<64, 256, 0, stream>>>(part, b_dec, dp);
    k3_fused<<<NCH, 256, 0, stream>>>(pre, enc, dp, wg, bg, mask,
                                      e_sc, m_arr, s_arr, cpart);
    k4_final<<<32, 256, 0, stream>>>(m_arr, s_arr, cpart, e_sc, c_out, w_out);
}

// Round 12
// 42.377 us; speedup vs baseline: 1.2793x; 1.2793x over previous
//
#include <hip/hip_runtime.h>
#include <math.h>

#define TT   16384
#define ADIM 1024
#define NCH  2048    // k3 blocks (8 rows each)
#define RPB  8       // rows per block
#define NCH2 128     // second-level context chunks (fold 16 each)

// fast tanh: 1 - 2/(e^{2x}+1); saturates correctly for large |x|
__device__ __forceinline__ float ftanh(float x) {
    float e2 = __expf(2.0f * x);
    return 1.0f - 2.0f * __builtin_amdgcn_rcpf(e2 + 1.0f);
}

__device__ __forceinline__ float pdot(float4 p, float4 d, float4 g) {
    return ftanh(p.x + d.x) * g.x + ftanh(p.y + d.y) * g.y +
           ftanh(p.z + d.z) * g.z + ftanh(p.w + d.w) * g.w;
}

// K1: dec GEMV partials. grid=256, block b handles rows [4b, 4b+4)
__global__ void k1_gemv_part(const float* __restrict__ z, const float* __restrict__ W,
                             float* __restrict__ part) {
    int b = blockIdx.x, tid = threadIdx.x;
    float4 acc = {0.f, 0.f, 0.f, 0.f};
#pragma unroll
    for (int i = 0; i < 4; ++i) {
        int d = b * 4 + i;
        float zv = z[d];
        float4 w4 = reinterpret_cast<const float4*>(W)[(size_t)d * 256 + tid];
        acc.x += zv * w4.x; acc.y += zv * w4.y; acc.z += zv * w4.z; acc.w += zv * w4.w;
    }
    reinterpret_cast<float4*>(part)[(size_t)b * 256 + tid] = acc;
}

// K2: reduce 256 partials -> dp[1024]. grid=64, block b covers cols [16b,16b+16)
__global__ void k2_gemv_red(const float* __restrict__ part, const float* __restrict__ bdec,
                            float* __restrict__ dp) {
    int b = blockIdx.x, tid = threadIdx.x;
    int lane = tid & 63, wv = tid >> 6;
    int rsub = lane >> 2;
    int colg = lane & 3;
    float4 acc = {0.f, 0.f, 0.f, 0.f};
#pragma unroll
    for (int i = 0; i < 4; ++i) {
        int row = i * 64 + wv * 16 + rsub;
        float4 v = reinterpret_cast<const float4*>(part)[(size_t)row * 256 + b * 4 + colg];
        acc.x += v.x; acc.y += v.y; acc.z += v.z; acc.w += v.w;
    }
#pragma unroll
    for (int off = 4; off <= 32; off <<= 1) {
        acc.x += __shfl_xor(acc.x, off, 64);
        acc.y += __shfl_xor(acc.y, off, 64);
        acc.z += __shfl_xor(acc.z, off, 64);
        acc.w += __shfl_xor(acc.w, off, 64);
    }
    __shared__ float4 lds[4][4];
    if (lane < 4) lds[wv][lane] = acc;
    __syncthreads();
    if (tid < 4) {
        float4 t = {0.f, 0.f, 0.f, 0.f};
#pragma unroll
        for (int w = 0; w < 4; ++w) {
            float4 v = lds[w][tid];
            t.x += v.x; t.y += v.y; t.z += v.z; t.w += v.w;
        }
        float4 bd = reinterpret_cast<const float4*>(bdec)[b * 4 + tid];
        t.x += bd.x; t.y += bd.y; t.z += bd.z; t.w += bd.w;
        reinterpret_cast<float4*>(dp)[b * 4 + tid] = t;
    }
}

// K3a: e-scores only — pure single-stream reader of pre.
// grid=NCH x 256. Block b rows [8b,8b+8). Wave wv owns cols [256wv,256wv+256).
__global__ void __launch_bounds__(256) k3a_escore(
    const float* __restrict__ pre, const float* __restrict__ dp,
    const float* __restrict__ wg, const float* __restrict__ bgp,
    const float* __restrict__ mask, float* __restrict__ e_out) {
    int b = blockIdx.x, tid = threadIdx.x;
    int lane = tid & 63, wv = tid >> 6;
    int col = wv * 64 + lane;
    float4 d4 = reinterpret_cast<const float4*>(dp)[col];
    float4 g4 = reinterpret_cast<const float4*>(wg)[col];
    float bgv = bgp[0];
    int t0 = b * RPB;
    const float4* pb = reinterpret_cast<const float4*>(pre) + (size_t)t0 * 256 + col;

    float dt[RPB];
#pragma unroll
    for (int r = 0; r < RPB; ++r) dt[r] = pdot(pb[r * 256], d4, g4);
#pragma unroll
    for (int r = 0; r < RPB; ++r) {
#pragma unroll
        for (int off = 32; off; off >>= 1) dt[r] += __shfl_xor(dt[r], off, 64);
    }
    __shared__ float sd[4][RPB];
    if (lane == 0) {
#pragma unroll
        for (int r = 0; r < RPB; ++r) sd[wv][r] = dt[r];
    }
    __syncthreads();
    if (tid < RPB) {
        float et = 2.0f * (sd[0][tid] + sd[1][tid] + sd[2][tid] + sd[3][tid]
                           + bgv + mask[t0 + tid]);
        e_out[t0 + tid] = et;
    }
}

// K3b: context partials — pure single-stream reader of enc.
// grid=NCH x 256. Block b reads its 8 e-values (32B, broadcast), computes
// chunk-local m,s,p, streams enc rows, writes cpart + m/s.
__global__ void __launch_bounds__(256) k3b_ctx(
    const float* __restrict__ enc, const float* __restrict__ e,
    float* __restrict__ m_out, float* __restrict__ s_out,
    float* __restrict__ cpart) {
    int b = blockIdx.x, tid = threadIdx.x;
    int lane = tid & 63, wv = tid >> 6;
    int col = wv * 64 + lane;
    int t0 = b * RPB;
    const float4* eb = reinterpret_cast<const float4*>(enc) + (size_t)t0 * 256 + col;

    float et[RPB];
#pragma unroll
    for (int r = 0; r < RPB; ++r) et[r] = e[t0 + r];
    float m = et[0];
#pragma unroll
    for (int r = 1; r < RPB; ++r) m = fmaxf(m, et[r]);
    float p[RPB], s = 0.f;
#pragma unroll
    for (int r = 0; r < RPB; ++r) { p[r] = __expf(et[r] - m); s += p[r]; }
    if (tid == 0) { m_out[b] = m; s_out[b] = s; }

    float4 ca = {0.f, 0.f, 0.f, 0.f};
#pragma unroll
    for (int r = 0; r < RPB; ++r) {
        float4 ev = eb[r * 256];
        ca.x += p[r] * ev.x; ca.y += p[r] * ev.y;
        ca.z += p[r] * ev.z; ca.w += p[r] * ev.w;
    }
    reinterpret_cast<float4*>(cpart)[(size_t)b * 256 + col] = ca;
}

// K4: global M,S + fold NCH chunk partials -> NCH2. grid=NCH2 blocks.
__global__ void __launch_bounds__(256) k4_fold(
    const float* __restrict__ m_arr, const float* __restrict__ s_arr,
    const float* __restrict__ cpart, float* __restrict__ cpart2,
    float* __restrict__ msout) {
    int b = blockIdx.x, tid = threadIdx.x;
    int lane = tid & 63, wv = tid >> 6;
    __shared__ float redm[4], reds[4];
    float mloc = -3.0e38f;
#pragma unroll
    for (int i = 0; i < NCH / 256; ++i) mloc = fmaxf(mloc, m_arr[tid + i * 256]);
#pragma unroll
    for (int off = 32; off; off >>= 1) mloc = fmaxf(mloc, __shfl_xor(mloc, off, 64));
    if (lane == 0) redm[wv] = mloc;
    __syncthreads();
    float M = fmaxf(fmaxf(redm[0], redm[1]), fmaxf(redm[2], redm[3]));
    float4 acc = {0.f, 0.f, 0.f, 0.f};
#pragma unroll
    for (int i = 0; i < NCH / NCH2; ++i) {
        int r = b * (NCH / NCH2) + i;
        float scf = __expf(m_arr[r] - M);
        float4 v = reinterpret_cast<const float4*>(cpart)[(size_t)r * 256 + tid];
        acc.x += scf * v.x; acc.y += scf * v.y; acc.z += scf * v.z; acc.w += scf * v.w;
    }
    reinterpret_cast<float4*>(cpart2)[(size_t)b * 256 + tid] = acc;
    if (b == 0) {
        float sl = 0.f;
#pragma unroll
        for (int i = 0; i < NCH / 256; ++i)
            sl += s_arr[tid + i * 256] * __expf(m_arr[tid + i * 256] - M);
#pragma unroll
        for (int off = 32; off; off >>= 1) sl += __shfl_xor(sl, off, 64);
        if (lane == 0) reds[wv] = sl;
        __syncthreads();
        if (tid == 0) {
            float S = reds[0] + reds[1] + reds[2] + reds[3];
            msout[0] = M;
            msout[1] = 1.0f / S;
        }
    }
}

// K5: final. blocks 0..15: c columns; blocks 16..31: w = exp(e-M)*invS.
__global__ void __launch_bounds__(256) k5_final(
    const float* __restrict__ cpart2, const float* __restrict__ e,
    const float* __restrict__ ms, float* __restrict__ c_out,
    float* __restrict__ w_out) {
    int b = blockIdx.x, tid = threadIdx.x;
    float M = ms[0], invS = ms[1];
    if (b < 16) {
        int rs = tid >> 4;   // 0..15 row-groups
        int cg = tid & 15;   // float4 group within block's 64 cols
        float4 acc = {0.f, 0.f, 0.f, 0.f};
#pragma unroll
        for (int i = 0; i < NCH2 / 16; ++i) {
            int r = rs * (NCH2 / 16) + i;
            float4 v = reinterpret_cast<const float4*>(cpart2)[(size_t)r * 256 + b * 16 + cg];
            acc.x += v.x; acc.y += v.y; acc.z += v.z; acc.w += v.w;
        }
        __shared__ float4 lds[16][16];
        lds[rs][cg] = acc;
        __syncthreads();
        if (tid < 16) {
            float4 t = {0.f, 0.f, 0.f, 0.f};
#pragma unroll
            for (int r = 0; r < 16; ++r) {
                float4 v = lds[r][tid];
                t.x += v.x; t.y += v.y; t.z += v.z; t.w += v.w;
            }
            t.x *= invS; t.y *= invS; t.z *= invS; t.w *= invS;
            reinterpret_cast<float4*>(c_out)[b * 16 + tid] = t;
        }
    } else {
        int base = (b - 16) * 256 + tid;
        float4 ev = reinterpret_cast<const float4*>(e)[base];
        float4 w;
        w.x = __expf(ev.x - M) * invS;
        w.y = __expf(ev.y - M) * invS;
        w.z = __expf(ev.z - M) * invS;
        w.w = __expf(ev.w - M) * invS;
        reinterpret_cast<float4*>(w_out)[base] = w;
    }
}

extern "C" void kernel_launch(void* const* d_in, const int* in_sizes, int n_in,
                              void* d_out, int out_size, void* d_ws, size_t ws_size,
                              hipStream_t stream) {
    const float* dec_z = (const float*)d_in[0];
    // d_in[1] = att_prev (unused)
    const float* pre   = (const float*)d_in[2];
    const float* enc   = (const float*)d_in[3];
    const float* mask  = (const float*)d_in[4];
    const float* W_dec = (const float*)d_in[5];
    const float* b_dec = (const float*)d_in[6];
    const float* wg    = (const float*)d_in[7];
    const float* bg    = (const float*)d_in[8];

    float* out   = (float*)d_out;
    float* c_out = out;            // [1024]
    float* w_out = out + ADIM;     // [16384]

    float* ws = (float*)d_ws;
    float* part   = ws;                           // 256*1024
    float* dp     = part + 256 * ADIM;            // 1024
    float* e_sc   = dp + ADIM;                    // 16384
    float* m_arr  = e_sc + TT;                    // NCH
    float* s_arr  = m_arr + NCH;                  // NCH
    float* cpart  = s_arr + NCH;                  // NCH*1024 (8.4MB)
    float* cpart2 = cpart + (size_t)NCH * ADIM;   // NCH2*1024
    float* ms     = cpart2 + (size_t)NCH2 * ADIM; // 2

    k1_gemv_part<<<256, 256, 0, stream>>>(dec_z, W_dec, part);
    k2_gemv_red<<<64, 256, 0, stream>>>(part, b_dec, dp);
    k3a_escore<<<NCH, 256, 0, stream>>>(pre, dp, wg, bg, mask, e_sc);
    k3b_ctx<<<NCH, 256, 0, stream>>>(enc, e_sc, m_arr, s_arr, cpart);
    k4_fold<<<NCH2, 256, 0, stream>>>(m_arr, s_arr, cpart, cpart2, ms);
    k5_final<<<32, 256, 0, stream>>>(cpart2, e_sc, ms, c_out, w_out);
}